// Round 7
// baseline (104.062 us; speedup 1.0000x reference)
//
#include <hip/hip_runtime.h>
#include <hip/hip_bf16.h>

#define LPOS 8192
#define HDIM 128
#define M_TOT 4096          // B*Cin
#define GROW  132           // gp/g row stride (129 used)
#define GELEMS (M_TOT * GROW)
#define KSPLIT 16
#define BK 512              // k per block: 8 iters of 64
#define BM 128              // rows per block
#define CUNITS 1024         // 16-B units per 64-k chunk of h2T

typedef float  f32x4 __attribute__((ext_vector_type(4)));
typedef short  s16x8 __attribute__((ext_vector_type(8)));
typedef unsigned int u32x2 __attribute__((ext_vector_type(2)));
typedef unsigned int u32x4 __attribute__((ext_vector_type(4)));

__device__ __forceinline__ unsigned short bf16_rne(float f) {
    unsigned u = __builtin_bit_cast(unsigned, f);
    u += 0x7fffu + ((u >> 16) & 1u);
    return (unsigned short)(u >> 16);
}

// ---------------- Kernel 1: SIREN -> h2T -------------------------------------
// h2T 16-B units: unit = chunk*1024 + k8*128 + h   (chunk = l/64, k8 = (l/8)%8)
__global__ __launch_bounds__(256) void k1_siren(
        const float* __restrict__ w1, const float* __restrict__ b1,
        const float* __restrict__ w2, const float* __restrict__ b2,
        unsigned short* __restrict__ h2T) {
    __shared__ float w2sT[HDIM * 129];
    __shared__ __align__(16) float h1s[2][HDIM * 8];
    const int tid = threadIdx.x;
    const int s = tid >> 7;
    const int h = tid & 127;

    for (int idx = tid; idx < HDIM * HDIM; idx += 256)
        w2sT[(idx & 127) * 129 + (idx >> 7)] = w2[idx];

    const int l0 = blockIdx.x * 16 + s * 8;
    const float myw1 = w1[h], myb1 = b1[h];
    #pragma unroll
    for (int ls = 0; ls < 8; ++ls) {
        float rel = -1.0f + (2.0f / 8191.0f) * (float)(l0 + ls);
        h1s[s][h * 8 + ls] = __sinf(30.0f * (rel * myw1 + myb1));
    }
    __syncthreads();

    const float bb = b2[h];
    float acc[8];
    #pragma unroll
    for (int ls = 0; ls < 8; ++ls) acc[ls] = bb;

    for (int j = 0; j < HDIM; ++j) {
        float wv = w2sT[j * 129 + h];
        const f32x4* hp = (const f32x4*)&h1s[s][j * 8];
        f32x4 p0 = hp[0], p1 = hp[1];
        acc[0] += wv * p0[0]; acc[1] += wv * p0[1];
        acc[2] += wv * p0[2]; acc[3] += wv * p0[3];
        acc[4] += wv * p1[0]; acc[5] += wv * p1[1];
        acc[6] += wv * p1[2]; acc[7] += wv * p1[3];
    }

    u32x4 ov;
    #pragma unroll
    for (int q = 0; q < 4; ++q) {
        unsigned lo = bf16_rne(__sinf(30.0f * acc[2 * q]));
        unsigned hi = bf16_rne(__sinf(30.0f * acc[2 * q + 1]));
        ov[q] = lo | (hi << 16);
    }
    const size_t c = (size_t)(l0 >> 6);
    const int k8 = (l0 >> 3) & 7;
    *(u32x4*)(h2T + (c * CUNITS + (size_t)k8 * 128 + h) * 8) = ov;
}

// ---------------- Kernel 2: deep-pipeline partial GEMM -----------------------
// 512 blocks (32 m x 16 y) = exactly 2/CU. Per iter (64 k): x loaded 2 iters
// ahead (8 independent dwordx4/thread in flight), B staged 1 ahead via
// global_load_lds with counted vmcnt(8) (gll issued BEFORE the x burst, so
// vmcnt(8) proves gll done while x stays in flight). One barrier per iter.
__global__ __launch_bounds__(256, 2) void k2_gemm(
        const float* __restrict__ x, const unsigned short* __restrict__ h2T,
        unsigned short* __restrict__ gp) {
    __shared__ unsigned short xb[2][BM * 64];       // 2 x 16 KB bf16, swizzled
    __shared__ unsigned short bs[2][CUNITS * 8];    // 2 x 16 KB

    const int bid = blockIdx.x;                     // 0..511
    const int swz = (bid & 7) * 64 + (bid >> 3);    // bijective; same-XCD -> same y pair
    const int m0 = (swz & 31) * BM;
    const int y  = swz >> 5;

    const int t    = threadIdx.x;
    const int lane = t & 63;
    const int w    = t >> 6;
    const int r    = lane & 15;
    const int kg   = lane >> 4;                     // 0..3
    const int rbase = (w >> 1) * 64;                // wave: 64 rows x 64 cols
    const int cbase = (w & 1) * 64;

    const float* xbase = x + (size_t)m0 * LPOS + (size_t)y * BK;
    const unsigned short* bsrc = h2T + (size_t)(y * 8) * (CUNITS * 8);

    f32x4 xr[2][8];
    float rsum[8] = {0.f,0.f,0.f,0.f,0.f,0.f,0.f,0.f};
    f32x4 acc[4][4];
    #pragma unroll
    for (int a = 0; a < 4; ++a)
        #pragma unroll
        for (int b = 0; b < 4; ++b) { f32x4 z = {0.f,0.f,0.f,0.f}; acc[a][b] = z; }

#define FENCE asm volatile("" ::: "memory")

#define GLLB(IT) do { \
    const unsigned short* s_ = bsrc + (size_t)(IT) * (CUNITS * 8); \
    unsigned short* d_ = &bs[(IT) & 1][0]; \
    _Pragma("unroll") for (int j_ = 0; j_ < 4; ++j_) { \
        const int U_ = j_ * 256 + t; \
        __builtin_amdgcn_global_load_lds((const unsigned int*)(s_ + (size_t)U_ * 8), \
                                         (unsigned int*)(d_ + U_ * 8), 16, 0, 0); } \
  } while (0)

    // x granule G = j*256+t: row = G>>4, 16-B col (G&15)*4. Per wave-instr:
    // 4 rows x 256 B contiguous -> every 64-B sector requested exactly once.
#define LOADX(IT) do { \
    const float* p_ = xbase + (IT) * 64; \
    _Pragma("unroll") for (int j_ = 0; j_ < 8; ++j_) { \
        const int G_ = j_ * 256 + t; \
        xr[(IT) & 1][j_] = *(const f32x4*)(p_ + (size_t)(G_ >> 4) * LPOS + (G_ & 15) * 4); } \
  } while (0)

    // write 8 B at row*128 + ((g16 ^ (row&7))*16) + (t&1)*8 : conflict-free
#define CVTW(IT) do { \
    const int sl_ = (IT) & 1; \
    _Pragma("unroll") for (int j_ = 0; j_ < 8; ++j_) { \
        const int G_ = j_ * 256 + t; \
        const int row_ = G_ >> 4; \
        const int g16_ = ((t & 15) >> 1) ^ (row_ & 7); \
        f32x4 v_ = xr[sl_][j_]; \
        rsum[j_] += (v_[0] + v_[1]) + (v_[2] + v_[3]); \
        u32x2 dv_; \
        dv_[0] = (unsigned)bf16_rne(v_[0]) | ((unsigned)bf16_rne(v_[1]) << 16); \
        dv_[1] = (unsigned)bf16_rne(v_[2]) | ((unsigned)bf16_rne(v_[3]) << 16); \
        *(u32x2*)&xb[sl_][row_ * 64 + g16_ * 8 + (t & 1) * 4] = dv_; } \
  } while (0)

#define COMPUTE(IT) do { \
    const int bf_ = (IT) & 1; \
    s16x8 af_[4][2], bfr_[4][2]; \
    _Pragma("unroll") for (int rg_ = 0; rg_ < 4; ++rg_) \
      _Pragma("unroll") for (int c_ = 0; c_ < 2; ++c_) { \
        const int arow_ = rbase + rg_ * 16 + r; \
        af_[rg_][c_] = *(const s16x8*)&xb[bf_][arow_ * 64 + (((c_ * 4 + kg) ^ (arow_ & 7)) * 8)]; } \
    _Pragma("unroll") for (int ct_ = 0; ct_ < 4; ++ct_) \
      _Pragma("unroll") for (int c_ = 0; c_ < 2; ++c_) { \
        const int h_ = cbase + ct_ * 16 + r; \
        bfr_[ct_][c_] = *(const s16x8*)&bs[bf_][((c_ * 4 + kg) * 128 + h_) * 8]; } \
    _Pragma("unroll") for (int rg_ = 0; rg_ < 4; ++rg_) \
      _Pragma("unroll") for (int ct_ = 0; ct_ < 4; ++ct_) \
        _Pragma("unroll") for (int c_ = 0; c_ < 2; ++c_) \
          acc[rg_][ct_] = __builtin_amdgcn_mfma_f32_16x16x32_bf16(af_[rg_][c_], bfr_[ct_][c_], acc[rg_][ct_], 0, 0, 0); \
  } while (0)

    // prologue: x0[8], gll0[4], x1[8] -> after cvt0's implicit x0 wait,
    // vmcnt(8) leaves only x1 -> gll0 complete.
    LOADX(0); FENCE; GLLB(0); FENCE; LOADX(1);
    CVTW(0);
    asm volatile("s_waitcnt vmcnt(8) lgkmcnt(0)" ::: "memory");
    __builtin_amdgcn_s_barrier();

#define BODY(I) \
    GLLB(I + 1); FENCE; LOADX(I + 2); \
    COMPUTE(I); \
    CVTW(I + 1); \
    asm volatile("s_waitcnt vmcnt(8) lgkmcnt(0)" ::: "memory"); \
    __builtin_amdgcn_s_barrier();

    BODY(0) BODY(1) BODY(2) BODY(3) BODY(4) BODY(5)

    // iter 6: no more x to load
    GLLB(7); FENCE;
    COMPUTE(6);
    CVTW(7);
    asm volatile("s_waitcnt vmcnt(0) lgkmcnt(0)" ::: "memory");
    __builtin_amdgcn_s_barrier();
    COMPUTE(7);

#undef BODY
#undef COMPUTE
#undef CVTW
#undef LOADX
#undef GLLB
#undef FENCE

    // epilogue: C/D layout col = 16*tile + r, row = base + kg*4 + q
    unsigned short* gpy = gp + (size_t)y * GELEMS;
    #pragma unroll
    for (int rg = 0; rg < 4; ++rg) {
        #pragma unroll
        for (int ct = 0; ct < 4; ++ct) {
            const int col = cbase + ct * 16 + r;
            #pragma unroll
            for (int q = 0; q < 4; ++q) {
                const int row = m0 + rbase + rg * 16 + kg * 4 + q;
                gpy[(size_t)row * GROW + col] = bf16_rne(acc[rg][ct][q]);
            }
        }
    }
    // col 128 = row-sums (b3 carrier): 16 lanes share row j*16 + (t>>4)
    #pragma unroll
    for (int j = 0; j < 8; ++j) {
        float v = rsum[j];
        v += __shfl_xor(v, 1); v += __shfl_xor(v, 2);
        v += __shfl_xor(v, 4); v += __shfl_xor(v, 8);
        if ((t & 15) == 0)
            gpy[(size_t)(m0 + j * 16 + (t >> 4)) * GROW + 128] = bf16_rne(v);
    }
}

// ---------------- reduce: g[f] = sum_y gp[y][f]  (bf16 -> f32) ---------------
__global__ __launch_bounds__(256) void reduce_g(
        const unsigned short* __restrict__ gp, float* __restrict__ g) {
    const int t = blockIdx.x * 256 + threadIdx.x;
    const unsigned int* p = (const unsigned int*)gp;
    float s0 = 0.f, s1 = 0.f, s2 = 0.f, s3 = 0.f;
    #pragma unroll
    for (int y = 0; y < KSPLIT; ++y) {
        u32x2 v = *(const u32x2*)(p + (size_t)y * (GELEMS / 2) + (size_t)t * 2);
        s0 += __builtin_bit_cast(float, v[0] << 16);
        s1 += __builtin_bit_cast(float, v[0] & 0xffff0000u);
        s2 += __builtin_bit_cast(float, v[1] << 16);
        s3 += __builtin_bit_cast(float, v[1] & 0xffff0000u);
    }
    f32x4 o = {s0, s1, s2, s3};
    *(f32x4*)(g + (size_t)t * 4) = o;
}

// ---------------- Kernel 3: out[b,o] = sum_{i,h} g[b,i,h]*w3e[o*64+i,h] ------
__global__ __launch_bounds__(256) void k3_contract(
        const float* __restrict__ g, const float* __restrict__ w3,
        const float* __restrict__ b3, const float* __restrict__ bias,
        float* __restrict__ out) {
    const int b = blockIdx.x >> 6;
    const int o = blockIdx.x & 63;
    const int t = threadIdx.x;
    const int i = t >> 2;
    const int q = t & 3;
    __shared__ float red[64];

    const float* gi = g + (size_t)(b * 64 + i) * GROW + q * 32;
    const float* wi = w3 + (size_t)(o * 64 + i) * HDIM + q * 32;
    float acc = 0.f;
    #pragma unroll
    for (int j = 0; j < 8; ++j) {
        f32x4 gv = *(const f32x4*)(gi + j * 4);
        f32x4 wv = *(const f32x4*)(wi + j * 4);
        acc += gv[0] * wv[0] + gv[1] * wv[1] + gv[2] * wv[2] + gv[3] * wv[3];
    }
    if (q == 0) acc += g[(size_t)(b * 64 + i) * GROW + 128] * b3[o * 64 + i];
    acc += __shfl_xor(acc, 1);
    acc += __shfl_xor(acc, 2);
    if (q == 0) red[i] = acc;
    __syncthreads();
    if (t < 64) {
        float v = red[t];
        v += __shfl_xor(v, 1);  v += __shfl_xor(v, 2);  v += __shfl_xor(v, 4);
        v += __shfl_xor(v, 8);  v += __shfl_xor(v, 16); v += __shfl_xor(v, 32);
        if (t == 0) out[blockIdx.x] = v + bias[o];
    }
}

extern "C" void kernel_launch(void* const* d_in, const int* in_sizes, int n_in,
                              void* d_out, int out_size, void* d_ws, size_t ws_size,
                              hipStream_t stream) {
    (void)in_sizes; (void)n_in; (void)out_size; (void)ws_size;
    const float* x    = (const float*)d_in[0];
    const float* w1   = (const float*)d_in[1];
    const float* b1   = (const float*)d_in[2];
    const float* w2   = (const float*)d_in[3];
    const float* b2   = (const float*)d_in[4];
    const float* w3   = (const float*)d_in[5];
    const float* b3   = (const float*)d_in[6];
    const float* bias = (const float*)d_in[7];
    float* out = (float*)d_out;

    unsigned short* h2T = (unsigned short*)d_ws;                       // 2.10 MB
    const size_t H2T_BYTES = (size_t)(LPOS / 64) * CUNITS * 16;
    unsigned short* gp = (unsigned short*)((char*)d_ws + H2T_BYTES);   // 17.3 MB
    const size_t GP_BYTES = (size_t)KSPLIT * GELEMS * 2;
    float* g = (float*)((char*)d_ws + H2T_BYTES + GP_BYTES);           // 2.16 MB

    k1_siren<<<LPOS / 16, 256, 0, stream>>>(w1, b1, w2, b2, h2T);
    k2_gemm<<<(M_TOT / BM) * KSPLIT, 256, 0, stream>>>(x, h2T, gp);
    reduce_g<<<GELEMS / 4 / 256, 256, 0, stream>>>(gp, g);
    k3_contract<<<64 * 64, 256, 0, stream>>>(g, w3, b3, bias, out);
}